// Round 3
// baseline (619.813 us; speedup 1.0000x reference)
//
#include <hip/hip_runtime.h>
#include <cfloat>

#define NTOK (64 * 4096)   // 262144 tokens
#define HID  128
#define NE   64
#define TK   6
#define TPT  2             // tokens per thread (W reuse factor)
#define BLK  256
#define GRID (NTOK / (BLK * TPT))   // 512 blocks -> 2 blocks/CU

// Per-token epilogue: top-6 -> outputs, then acc[] -> softmax probs in place.
__device__ __forceinline__ void process_token(float (&acc)[NE], int token,
                                              float* __restrict__ oidx,
                                              float* __restrict__ ow,
                                              int (&ti_out)[TK])
{
    float tv[TK];
    int   ti[TK];
#pragma unroll
    for (int q = 0; q < TK; ++q) { tv[q] = -FLT_MAX; ti[q] = 0; }

#pragma unroll
    for (int e = 0; e < NE; ++e) {
        float m = acc[e];
        int   mi = e;
#pragma unroll
        for (int q = 0; q < TK; ++q) {
            const bool  c  = m > tv[q];        // strict >: jax stable tie order
            const float nt = c ? m     : tv[q];
            const float nm = c ? tv[q] : m;
            const int   ni = c ? mi    : ti[q];
            const int   nj = c ? ti[q] : mi;
            tv[q] = nt; m = nm; ti[q] = ni; mi = nj;
        }
    }

    const float mx = tv[0];
    float ex[TK];
    float s = 0.0f;
#pragma unroll
    for (int q = 0; q < TK; ++q) { ex[q] = __expf(tv[q] - mx); s += ex[q]; }
    const float rs = 1.0f / (s + 1e-20f);

    const size_t gt = (size_t)token * TK;
    float2* ip = (float2*)(oidx + gt);
    float2* wp = (float2*)(ow + gt);
    ip[0] = make_float2((float)ti[0], (float)ti[1]);
    ip[1] = make_float2((float)ti[2], (float)ti[3]);
    ip[2] = make_float2((float)ti[4], (float)ti[5]);
    wp[0] = make_float2(ex[0]*rs, ex[1]*rs);
    wp[1] = make_float2(ex[2]*rs, ex[3]*rs);
    wp[2] = make_float2(ex[4]*rs, ex[5]*rs);

#pragma unroll
    for (int q = 0; q < TK; ++q) ti_out[q] = ti[q];

    // full softmax probs in place (for aux-loss Pi)
    float Z = 0.0f;
#pragma unroll
    for (int e = 0; e < NE; ++e) { acc[e] = __expf(acc[e] - mx); Z += acc[e]; }
    const float rz = 1.0f / Z;
#pragma unroll
    for (int e = 0; e < NE; ++e) acc[e] *= rz;
}

__global__ __launch_bounds__(BLK, 2)
void gate_kernel(const float* __restrict__ X,
                 const float* __restrict__ W,
                 float* __restrict__ oidx,
                 float* __restrict__ ow,
                 float* __restrict__ Pi_g,
                 unsigned int* __restrict__ cnt_g)
{
    __shared__ float        Wt[HID][NE];   // transposed: Wt[k][e], 32 KB
    __shared__ float        Pi_s[NE];
    __shared__ unsigned int cnt_s[NE];

    const int tid  = threadIdx.x;
    const int lane = tid & 63;

    if (tid < NE) { Pi_s[tid] = 0.0f; cnt_s[tid] = 0u; }

    // ---- stage W -> LDS transposed (one-time; bank conflicts don't matter here)
    {
        const float4* W4 = (const float4*)W;
#pragma unroll
        for (int i = 0; i < 8; ++i) {
            const int flat = tid + i * BLK;        // [0, 2048) float4 index
            const float4 v = W4[flat];
            const int e  = flat >> 5;              // 32 float4 per expert row
            const int k0 = (flat & 31) << 2;
            Wt[k0+0][e] = v.x; Wt[k0+1][e] = v.y;
            Wt[k0+2][e] = v.z; Wt[k0+3][e] = v.w;
        }
    }
    __syncthreads();

    const int tokenA = blockIdx.x * (BLK * TPT) + tid;
    const int tokenB = tokenA + BLK;
    const float4* xa = (const float4*)(X + (size_t)tokenA * HID);
    const float4* xb = (const float4*)(X + (size_t)tokenB * HID);

    float accA[NE], accB[NE];
#pragma unroll
    for (int e = 0; e < NE; ++e) { accA[e] = 0.0f; accB[e] = 0.0f; }

    // ---- logits: W from LDS (uniform ds_read_b128 broadcast), x from global
#pragma unroll 1
    for (int c = 0; c < 8; ++c) {          // k-chunks of 16
        float xA[16], xB[16];
#pragma unroll
        for (int j = 0; j < 4; ++j) {
            const float4 va = xa[c*4 + j];
            xA[4*j+0] = va.x; xA[4*j+1] = va.y; xA[4*j+2] = va.z; xA[4*j+3] = va.w;
            const float4 vb = xb[c*4 + j];
            xB[4*j+0] = vb.x; xB[4*j+1] = vb.y; xB[4*j+2] = vb.z; xB[4*j+3] = vb.w;
        }
#pragma unroll
        for (int kk = 0; kk < 16; ++kk) {
            const float4* wrow = (const float4*)&Wt[c*16 + kk][0];
#pragma unroll
            for (int q = 0; q < 16; ++q) {
                const float4 w = wrow[q];          // experts 4q..4q+3, uniform
                accA[4*q+0] = fmaf(xA[kk], w.x, accA[4*q+0]);
                accA[4*q+1] = fmaf(xA[kk], w.y, accA[4*q+1]);
                accA[4*q+2] = fmaf(xA[kk], w.z, accA[4*q+2]);
                accA[4*q+3] = fmaf(xA[kk], w.w, accA[4*q+3]);
                accB[4*q+0] = fmaf(xB[kk], w.x, accB[4*q+0]);
                accB[4*q+1] = fmaf(xB[kk], w.y, accB[4*q+1]);
                accB[4*q+2] = fmaf(xB[kk], w.z, accB[4*q+2]);
                accB[4*q+3] = fmaf(xB[kk], w.w, accB[4*q+3]);
            }
        }
    }

    // ---- per-token epilogues (acc arrays become softmax probs)
    int tiA[TK], tiB[TK];
    process_token(accA, tokenA, oidx, ow, tiA);
    process_token(accB, tokenB, oidx, ow, tiB);

#pragma unroll
    for (int q = 0; q < TK; ++q) atomicAdd(&cnt_s[tiA[q]], 1u);
#pragma unroll
    for (int q = 0; q < TK; ++q) atomicAdd(&cnt_s[tiB[q]], 1u);

    // ---- Pi: merge both tokens, then 63-shuffle recursive-halving
    //      transpose-reduce: lane l ends up with expert l's wave sum.
#pragma unroll
    for (int e = 0; e < NE; ++e) accA[e] += accB[e];

#pragma unroll
    for (int s = 32; s >= 1; s >>= 1) {
        const bool up = (lane & s) != 0;
#pragma unroll
        for (int i = 0; i < s; ++i) {
            const float lo = accA[i], hi = accA[i + s];
            const float send = up ? lo : hi;
            const float recv = __shfl_xor(send, s);
            accA[i] = (up ? hi : lo) + recv;
        }
    }
    atomicAdd(&Pi_s[lane], accA[0]);

    __syncthreads();
    if (tid < NE) {
        atomicAdd(&Pi_g[tid], Pi_s[tid]);
        atomicAdd(&cnt_g[tid], cnt_s[tid]);
    }
}

__global__ void aux_kernel(const float* __restrict__ Pi_g,
                           const unsigned int* __restrict__ cnt_g,
                           float* __restrict__ out_aux)
{
    const int e = threadIdx.x;   // 64 threads
    const float Pi = Pi_g[e] * (1.0f / (float)NTOK);
    const float ce = (float)cnt_g[e] * (1.0f / (float)(NTOK * TK));
    float v = Pi * ce * (float)NE;
#pragma unroll
    for (int off = 32; off > 0; off >>= 1) v += __shfl_down(v, off);
    if (e == 0) out_aux[0] = v * 1.0e-3f;
}

extern "C" void kernel_launch(void* const* d_in, const int* in_sizes, int n_in,
                              void* d_out, int out_size, void* d_ws, size_t ws_size,
                              hipStream_t stream) {
    const float* X = (const float*)d_in[0];
    const float* W = (const float*)d_in[1];

    float* out  = (float*)d_out;
    float* oidx = out;                          // N*6 indices (as float)
    float* ow   = out + (size_t)NTOK * TK;      // N*6 weights
    float* aux  = out + (size_t)NTOK * TK * 2;  // 1 scalar

    float*        Pi_g  = (float*)d_ws;
    unsigned int* cnt_g = (unsigned int*)((char*)d_ws + 256);

    hipMemsetAsync(d_ws, 0, 512, stream);
    gate_kernel<<<GRID, BLK, 0, stream>>>(X, W, oidx, ow, Pi_g, cnt_g);
    aux_kernel<<<1, 64, 0, stream>>>(Pi_g, cnt_g, aux);
}

// Round 4
// 257.974 us; speedup vs baseline: 2.4026x; 2.4026x over previous
//
#include <hip/hip_runtime.h>
#include <cfloat>

#define NTOK (64 * 4096)   // 262144 tokens
#define HID  128
#define NE   64
#define TK   6
#define BLK  256
#define GRID (NTOK / BLK)  // 1024 blocks -> 4 blocks/CU

__global__ __launch_bounds__(BLK, 4)
void gate_kernel(const float* __restrict__ X,
                 const float* __restrict__ W,
                 float* __restrict__ oidx,
                 float* __restrict__ ow,
                 float* __restrict__ Pi_g,
                 unsigned int* __restrict__ cnt_g)
{
    // Wt[k][col] with col = (e + 4*((k>>2)&15)) & 63.
    // - staging writes: <=2 lanes/bank (free)
    // - hot-loop reads: wave-uniform broadcast, rotation folded into
    //   compile-time offsets (no runtime index math)
    __shared__ float        Wt[HID][NE];   // 32 KB
    __shared__ float        Pi_s[NE];
    __shared__ unsigned int cnt_s[NE];

    const int tid  = threadIdx.x;
    const int lane = tid & 63;

    if (tid < NE) { Pi_s[tid] = 0.0f; cnt_s[tid] = 0u; }

    // ---- stage W -> LDS transposed+swizzled
    {
        const float4* W4 = (const float4*)W;
#pragma unroll
        for (int i = 0; i < 8; ++i) {
            const int flat = tid + i * BLK;        // [0, 2048) float4 index
            const float4 v = W4[flat];
            const int e   = flat >> 5;             // 32 float4 per expert row
            const int k0  = (flat & 31) << 2;      // k0..k0+3 share k>>2 = flat&31
            const int col = (e + ((flat & 15) << 2)) & 63;
            Wt[k0+0][col] = v.x; Wt[k0+1][col] = v.y;
            Wt[k0+2][col] = v.z; Wt[k0+3][col] = v.w;
        }
    }
    __syncthreads();

    const int token = blockIdx.x * BLK + tid;
    const float4* xrow = (const float4*)(X + (size_t)token * HID);

    float acc[NE];
#pragma unroll
    for (int e = 0; e < NE; ++e) acc[e] = 0.0f;

    // ---- logits: W via uniform ds_read_b128 broadcast, x per-lane from global
#pragma unroll 1
    for (int c = 0; c < 8; ++c) {          // k-chunks of 16
        float x[16];
#pragma unroll
        for (int j = 0; j < 4; ++j) {
            const float4 v = xrow[c*4 + j];
            x[4*j+0] = v.x; x[4*j+1] = v.y; x[4*j+2] = v.z; x[4*j+3] = v.w;
        }
#pragma unroll
        for (int kk = 0; kk < 16; ++kk) {
            const int row  = c*16 + kk;
            const int rot4 = (row >> 2) & 15;               // compile-time
            const float4* wrow = (const float4*)&Wt[row][0];
#pragma unroll
            for (int q = 0; q < 16; ++q) {                  // expert group 4q..4q+3
                const float4 w = wrow[(q + rot4) & 15];     // const offset
                acc[4*q+0] = fmaf(x[kk], w.x, acc[4*q+0]);
                acc[4*q+1] = fmaf(x[kk], w.y, acc[4*q+1]);
                acc[4*q+2] = fmaf(x[kk], w.z, acc[4*q+2]);
                acc[4*q+3] = fmaf(x[kk], w.w, acc[4*q+3]);
            }
        }
    }

    // ---- top-6 (branchless insertion, strict > keeps jax stable tie order)
    float tv[TK];
    int   ti[TK];
#pragma unroll
    for (int q = 0; q < TK; ++q) { tv[q] = -FLT_MAX; ti[q] = 0; }

#pragma unroll
    for (int e = 0; e < NE; ++e) {
        float m = acc[e];
        int   mi = e;
#pragma unroll
        for (int q = 0; q < TK; ++q) {
            const bool  c  = m > tv[q];
            const float nt = c ? m     : tv[q];
            const float nm = c ? tv[q] : m;
            const int   ni = c ? mi    : ti[q];
            const int   nj = c ? ti[q] : mi;
            tv[q] = nt; m = nm; ti[q] = ni; mi = nj;
        }
    }

    // ---- weights (renormalized top-6 softmax; Z cancels)
    const float mx = tv[0];
    float ex[TK];
    float s = 0.0f;
#pragma unroll
    for (int q = 0; q < TK; ++q) { ex[q] = __expf(tv[q] - mx); s += ex[q]; }
    const float rs = 1.0f / (s + 1e-20f);

    {
        const size_t gt = (size_t)token * TK;
        float2* ip = (float2*)(oidx + gt);
        float2* wp = (float2*)(ow + gt);
        ip[0] = make_float2((float)ti[0], (float)ti[1]);
        ip[1] = make_float2((float)ti[2], (float)ti[3]);
        ip[2] = make_float2((float)ti[4], (float)ti[5]);
        wp[0] = make_float2(ex[0]*rs, ex[1]*rs);
        wp[1] = make_float2(ex[2]*rs, ex[3]*rs);
        wp[2] = make_float2(ex[4]*rs, ex[5]*rs);
    }

#pragma unroll
    for (int q = 0; q < TK; ++q) atomicAdd(&cnt_s[ti[q]], 1u);

    // ---- full softmax probs for aux-loss Pi
    float Z = 0.0f;
#pragma unroll
    for (int e = 0; e < NE; ++e) { acc[e] = __expf(acc[e] - mx); Z += acc[e]; }
    const float rz = 1.0f / Z;
#pragma unroll
    for (int e = 0; e < NE; ++e) acc[e] *= rz;

    // 63-shuffle recursive-halving transpose-reduce: lane l gets expert l's wave sum
#pragma unroll
    for (int s = 32; s >= 1; s >>= 1) {
        const bool up = (lane & s) != 0;
#pragma unroll
        for (int i = 0; i < s; ++i) {
            const float lo = acc[i], hi = acc[i + s];
            const float send = up ? lo : hi;
            const float recv = __shfl_xor(send, s);
            acc[i] = (up ? hi : lo) + recv;
        }
    }
    atomicAdd(&Pi_s[lane], acc[0]);

    __syncthreads();
    if (tid < NE) {
        atomicAdd(&Pi_g[tid], Pi_s[tid]);
        atomicAdd(&cnt_g[tid], cnt_s[tid]);
    }
}

__global__ void aux_kernel(const float* __restrict__ Pi_g,
                           const unsigned int* __restrict__ cnt_g,
                           float* __restrict__ out_aux)
{
    const int e = threadIdx.x;   // 64 threads
    const float Pi = Pi_g[e] * (1.0f / (float)NTOK);
    const float ce = (float)cnt_g[e] * (1.0f / (float)(NTOK * TK));
    float v = Pi * ce * (float)NE;
#pragma unroll
    for (int off = 32; off > 0; off >>= 1) v += __shfl_down(v, off);
    if (e == 0) out_aux[0] = v * 1.0e-3f;
}

extern "C" void kernel_launch(void* const* d_in, const int* in_sizes, int n_in,
                              void* d_out, int out_size, void* d_ws, size_t ws_size,
                              hipStream_t stream) {
    const float* X = (const float*)d_in[0];
    const float* W = (const float*)d_in[1];

    float* out  = (float*)d_out;
    float* oidx = out;                          // N*6 indices (as float)
    float* ow   = out + (size_t)NTOK * TK;      // N*6 weights
    float* aux  = out + (size_t)NTOK * TK * 2;  // 1 scalar

    float*        Pi_g  = (float*)d_ws;
    unsigned int* cnt_g = (unsigned int*)((char*)d_ws + 256);

    hipMemsetAsync(d_ws, 0, 512, stream);
    gate_kernel<<<GRID, BLK, 0, stream>>>(X, W, oidx, ow, Pi_g, cnt_g);
    aux_kernel<<<1, 64, 0, stream>>>(Pi_g, cnt_g, aux);
}